// Round 6
// baseline (639.469 us; speedup 1.0000x reference)
//
#include <hip/hip_runtime.h>
#include <stdint.h>

#define N_ROWS 16384
#define M_ROWS 16384
#define KDIM   512
#define BM 128           // 2 waves x 64 rows
#define BNT 64           // cols per bt tile
#define BKP 128          // k per phase (one MFMA K)
#define NCHUNK 16
#define CHUNK_ROWS (M_ROWS / NCHUNK)       // 1024
#define BT_PER_CHUNK (CHUNK_ROWS / BNT)    // 16

typedef int intx4 __attribute__((ext_vector_type(4)));
typedef int intx8 __attribute__((ext_vector_type(8)));
typedef float floatx4 __attribute__((ext_vector_type(4)));

#define UNIT_SCALE 0x7F7F7F7F  // E8M0 exponent 127 -> 2^0 = 1.0 in every byte

__device__ __forceinline__ void async_ld16(const uint8_t* g, uint8_t* l) {
  __builtin_amdgcn_global_load_lds(
      (const __attribute__((address_space(1))) void*)g,
      (__attribute__((address_space(3))) void*)l, 16, 0, 0);
}

// Kernel 1: fp32 -> fp8 e4m3 (unit scale) + per-row squared norms (fp32).
// One wave per row; 16 waves/block.
__global__ void __launch_bounds__(1024)
conv_kernel(const float* __restrict__ A, const float* __restrict__ B,
            uint8_t* __restrict__ Ah8, uint8_t* __restrict__ Bh8,
            float* __restrict__ sq1, float* __restrict__ sq2) {
  const int lane = threadIdx.x & 63;
  const int wv = threadIdx.x >> 6;
  int row = blockIdx.x * 16 + wv;
  const float* src;
  uint8_t* dst;
  float* sq;
  if (row < N_ROWS) {
    src = A + (size_t)row * KDIM;
    dst = Ah8 + (size_t)row * KDIM;
    sq = sq1 + row;
  } else {
    int r = row - N_ROWS;
    src = B + (size_t)r * KDIM;
    dst = Bh8 + (size_t)r * KDIM;
    sq = sq2 + r;
  }
  const float4* s4 = (const float4*)src;
  float4 v0 = s4[lane * 2];
  float4 v1 = s4[lane * 2 + 1];
  uint32_t w0 = 0, w1 = 0;
  w0 = __builtin_amdgcn_cvt_pk_fp8_f32(v0.x, v0.y, w0, 0);
  w0 = __builtin_amdgcn_cvt_pk_fp8_f32(v0.z, v0.w, w0, 1);
  w1 = __builtin_amdgcn_cvt_pk_fp8_f32(v1.x, v1.y, w1, 0);
  w1 = __builtin_amdgcn_cvt_pk_fp8_f32(v1.z, v1.w, w1, 1);
  uint2 pk = {w0, w1};
  ((uint2*)dst)[lane] = pk;
  float s = v0.x * v0.x + v0.y * v0.y + v0.z * v0.z + v0.w * v0.w
          + v1.x * v1.x + v1.y * v1.y + v1.z * v1.z + v1.w * v1.w;
  #pragma unroll
  for (int off = 32; off; off >>= 1) s += __shfl_down(s, off, 64);
  if (lane == 0) *sq = s;
}

// Kernel 2: fused fp8 GEMM + running-min.
// 2 waves/block; wave wv owns A rows [wv*64, wv*64+64) fully in registers
// (areg[4][4] intx8 = 128 VGPRs, K=512 of fp8). B streams through LDS:
// double-buffered 2 x 8KB phases (64 cols x 128 k), XOR-swizzled 16B chunks.
// MFMA: mfma_scale 16x16x128 f8f6f4 FP8/FP8, unit scales.
// NCHUNK=16 -> 2048 blocks = 8 blocks/CU = 4 waves/SIMD (VGPR 128 exactly
// fits 4 waves; LDS 8x16KB=128KB fits) so barrier/DMA stalls of one block
// stream are filled by another's MFMAs.
// chunk = bid & 15; XCD = bid & 7 -> chunks c, c+8 pinned per XCD (1MB in L2).
__global__ void __launch_bounds__(128, 4)
gemm_min_kernel(const uint8_t* __restrict__ Ah8, const uint8_t* __restrict__ Bh8,
                const float* __restrict__ sq2, float* __restrict__ ws_min) {
  __shared__ __align__(16) uint8_t lsB[2][BNT * BKP];   // 2 x 8 KB

  const int tid = threadIdx.x;
  const int lane = tid & 63;
  const int wv = tid >> 6;       // 0..1
  const int fr = lane & 15;
  const int kg = lane >> 4;      // 0..3
  const int frs = fr & 7;

  const int bid = blockIdx.x;
  const int chunk = bid & 15;
  const int rowBase = (bid >> 4) * BM;
  const int colBase0 = chunk * CHUNK_ROWS;

  // Staging: 8 slots of 1KB per phase (slot = 8 cols x 128 B); wave wv does
  // slots [wv*4, wv*4+4). lane -> col-in-slot = lane>>3, chunk = lane&7.
  const int cis = lane >> 3;                       // col in slot
  const int kofs_st = (((lane & 7) ^ cis) << 4);   // swizzled 16B source chunk

  // ---- Persistent A fragments: areg[i][p] = row (rowBase+wv*64+i*16+fr),
  // k = p*128 + kg*32 .. +32.
  intx8 areg[4][4];
  {
    const uint8_t* abase = Ah8 + (size_t)(rowBase + wv * 64 + fr) * KDIM + kg * 32;
    #pragma unroll
    for (int i = 0; i < 4; i++)
      #pragma unroll
      for (int p = 0; p < 4; p++) {
        const uint8_t* ap = abase + (size_t)i * 16 * KDIM + p * BKP;
        intx4 lo = *(const intx4*)ap;
        intx4 hi = *(const intx4*)(ap + 16);
        areg[i][p] = __builtin_shufflevector(lo, hi, 0, 1, 2, 3, 4, 5, 6, 7);
      }
  }

  float runmin[4][4];
  #pragma unroll
  for (int i = 0; i < 4; i++)
    #pragma unroll
    for (int r4 = 0; r4 < 4; r4++) runmin[i][r4] = 3.0e38f;

  // Stage one 64-col x 128-k phase (8 KB): 4 wave-calls per wave.
  #define STAGE_B(buf, cb, kbase_)                                            \
    {                                                                         \
      _Pragma("unroll")                                                       \
      for (int c = 0; c < 4; ++c) {                                           \
        const int slot = wv * 4 + c;                                          \
        async_ld16(Bh8 + (size_t)((cb) + slot * 8 + cis) * KDIM +             \
                       (kbase_) + kofs_st,                                    \
                   (buf) + (slot << 10));                                     \
      }                                                                       \
    }

  STAGE_B(lsB[0], colBase0, 0)
  __syncthreads();

  for (int bt = 0; bt < BT_PER_CHUNK; ++bt) {
    const int colBase = colBase0 + bt * BNT;
    floatx4 acc[4][4];
    #pragma unroll
    for (int i = 0; i < 4; i++)
      #pragma unroll
      for (int j = 0; j < 4; j++) acc[i][j] = (floatx4){0.f, 0.f, 0.f, 0.f};

    #pragma unroll
    for (int p = 0; p < 4; ++p) {
      const uint8_t* cur = lsB[p & 1];
      if (p < 3) {
        STAGE_B(lsB[(p + 1) & 1], colBase, (p + 1) * BKP)
      } else if (bt + 1 < BT_PER_CHUNK) {
        STAGE_B(lsB[0], colBase + BNT, 0)
      }
      // Compute phase p: 16 MFMAs/wave.
      #pragma unroll
      for (int j = 0; j < 4; j++) {
        const uint8_t* bp = cur + (j * 16 + fr) * BKP;
        intx4 lo = *(const intx4*)(bp + ((((kg << 1)) ^ frs) << 4));
        intx4 hi = *(const intx4*)(bp + ((((kg << 1) | 1) ^ frs) << 4));
        intx8 bv = __builtin_shufflevector(lo, hi, 0, 1, 2, 3, 4, 5, 6, 7);
        #pragma unroll
        for (int i = 0; i < 4; i++)
          acc[i][j] = __builtin_amdgcn_mfma_scale_f32_16x16x128_f8f6f4(
              areg[i][p], bv, acc[i][j], 0, 0,
              0, UNIT_SCALE, 0, UNIT_SCALE);
      }
      __syncthreads();
    }

    // Epilogue: cand = sq2[col] - 2*inner -> per-row running min.
    #pragma unroll
    for (int j = 0; j < 4; j++) {
      const float s2 = sq2[colBase + j * 16 + fr];
      #pragma unroll
      for (int i = 0; i < 4; i++)
        #pragma unroll
        for (int r4 = 0; r4 < 4; r4++) {
          const float cand = fmaf(-2.f, acc[i][j][r4], s2);
          runmin[i][r4] = fminf(runmin[i][r4], cand);
        }
    }
  }

  // Min over the 16 columns per lane row-group: butterfly on lane bits 0..3.
  #pragma unroll
  for (int i = 0; i < 4; i++)
    #pragma unroll
    for (int r4 = 0; r4 < 4; r4++) {
      float v = runmin[i][r4];
      v = fminf(v, __shfl_xor(v, 1, 64));
      v = fminf(v, __shfl_xor(v, 2, 64));
      v = fminf(v, __shfl_xor(v, 4, 64));
      v = fminf(v, __shfl_xor(v, 8, 64));
      runmin[i][r4] = v;
    }

  if (fr == 0) {
    #pragma unroll
    for (int i = 0; i < 4; i++)
      #pragma unroll
      for (int r4 = 0; r4 < 4; r4++) {
        const int lrow = wv * 64 + i * 16 + kg * 4 + r4;
        ws_min[(size_t)chunk * N_ROWS + rowBase + lrow] = runmin[i][r4];
      }
  }
}

// Kernel 3a: per-row min across chunks + sqrt/relu, 64-block partial sums.
__global__ void partial_kernel(const float* __restrict__ ws_min,
                               const float* __restrict__ sq1,
                               float* __restrict__ part) {
  const int r = blockIdx.x * 256 + threadIdx.x;
  float m = ws_min[r];
  #pragma unroll
  for (int c = 1; c < NCHUNK; c++) m = fminf(m, ws_min[(size_t)c * N_ROWS + r]);
  float d2 = sq1[r] + m;
  d2 = d2 > 0.f ? d2 : 0.f;
  float v = sqrtf(d2) - 0.1f;
  float s = v > 0.f ? v : 0.f;
  #pragma unroll
  for (int off = 32; off; off >>= 1) s += __shfl_down(s, off, 64);
  __shared__ float ps[4];
  if ((threadIdx.x & 63) == 0) ps[threadIdx.x >> 6] = s;
  __syncthreads();
  if (threadIdx.x == 0) part[blockIdx.x] = ps[0] + ps[1] + ps[2] + ps[3];
}

// Kernel 3b: combine 64 partials.
__global__ void final_kernel(const float* __restrict__ part, float* __restrict__ out) {
  float s = part[threadIdx.x];
  #pragma unroll
  for (int off = 32; off; off >>= 1) s += __shfl_down(s, off, 64);
  if (threadIdx.x == 0) out[0] = s / (float)N_ROWS;
}

extern "C" void kernel_launch(void* const* d_in, const int* in_sizes, int n_in,
                              void* d_out, int out_size, void* d_ws, size_t ws_size,
                              hipStream_t stream) {
  const float* A = (const float*)d_in[0];
  const float* B = (const float*)d_in[1];
  char* ws = (char*)d_ws;
  const size_t fp8Bytes = (size_t)N_ROWS * KDIM;   // 8 MiB each
  uint8_t* Ah8 = (uint8_t*)ws;
  uint8_t* Bh8 = (uint8_t*)(ws + fp8Bytes);
  float* sq1 = (float*)(ws + 2 * fp8Bytes);
  float* sq2 = sq1 + N_ROWS;
  float* ws_min = sq2 + M_ROWS;
  float* part = ws_min + (size_t)NCHUNK * N_ROWS;

  conv_kernel<<<dim3((N_ROWS + M_ROWS) / 16), dim3(1024), 0, stream>>>(A, B, Ah8, Bh8, sq1, sq2);
  gemm_min_kernel<<<dim3((N_ROWS / BM) * NCHUNK), dim3(128), 0, stream>>>(Ah8, Bh8, sq2, ws_min);
  partial_kernel<<<dim3(64), dim3(256), 0, stream>>>(ws_min, sq1, part);
  final_kernel<<<dim3(1), dim3(64), 0, stream>>>(part, (float*)d_out);
}

// Round 7
// 214.407 us; speedup vs baseline: 2.9825x; 2.9825x over previous
//
#include <hip/hip_runtime.h>
#include <stdint.h>

#define N_ROWS 16384
#define M_ROWS 16384
#define KDIM   512
#define BM 64            // 1 wave x 64 rows per block
#define BNT 64           // cols per bt tile
#define BKP 128          // k per phase (one MFMA K)
#define NCHUNK 8
#define CHUNK_ROWS (M_ROWS / NCHUNK)       // 2048
#define BT_PER_CHUNK (CHUNK_ROWS / BNT)    // 32

typedef int intx4 __attribute__((ext_vector_type(4)));
typedef int intx8 __attribute__((ext_vector_type(8)));
typedef float floatx4 __attribute__((ext_vector_type(4)));

#define UNIT_SCALE 0x7F7F7F7F  // E8M0 exponent 127 -> 2^0 = 1.0 in every byte

__device__ __forceinline__ void async_ld16(const uint8_t* g, uint8_t* l) {
  __builtin_amdgcn_global_load_lds(
      (const __attribute__((address_space(1))) void*)g,
      (__attribute__((address_space(3))) void*)l, 16, 0, 0);
}

// Kernel 1: fp32 -> fp8 e4m3 (unit scale) + per-row squared norms (fp32).
// One wave per row; 16 waves/block.
__global__ void __launch_bounds__(1024)
conv_kernel(const float* __restrict__ A, const float* __restrict__ B,
            uint8_t* __restrict__ Ah8, uint8_t* __restrict__ Bh8,
            float* __restrict__ sq1, float* __restrict__ sq2) {
  const int lane = threadIdx.x & 63;
  const int wv = threadIdx.x >> 6;
  int row = blockIdx.x * 16 + wv;
  const float* src;
  uint8_t* dst;
  float* sq;
  if (row < N_ROWS) {
    src = A + (size_t)row * KDIM;
    dst = Ah8 + (size_t)row * KDIM;
    sq = sq1 + row;
  } else {
    int r = row - N_ROWS;
    src = B + (size_t)r * KDIM;
    dst = Bh8 + (size_t)r * KDIM;
    sq = sq2 + r;
  }
  const float4* s4 = (const float4*)src;
  float4 v0 = s4[lane * 2];
  float4 v1 = s4[lane * 2 + 1];
  uint32_t w0 = 0, w1 = 0;
  w0 = __builtin_amdgcn_cvt_pk_fp8_f32(v0.x, v0.y, w0, 0);
  w0 = __builtin_amdgcn_cvt_pk_fp8_f32(v0.z, v0.w, w0, 1);
  w1 = __builtin_amdgcn_cvt_pk_fp8_f32(v1.x, v1.y, w1, 0);
  w1 = __builtin_amdgcn_cvt_pk_fp8_f32(v1.z, v1.w, w1, 1);
  uint2 pk = {w0, w1};
  ((uint2*)dst)[lane] = pk;
  float s = v0.x * v0.x + v0.y * v0.y + v0.z * v0.z + v0.w * v0.w
          + v1.x * v1.x + v1.y * v1.y + v1.z * v1.z + v1.w * v1.w;
  #pragma unroll
  for (int off = 32; off; off >>= 1) s += __shfl_down(s, off, 64);
  if (lane == 0) *sq = s;
}

// Kernel 2: fused fp8 GEMM + running-min.
// SINGLE-WAVE workgroups: each block = 1 wave owning 64 A-rows fully in
// registers (areg[4][4] intx8 = 128 arch VGPRs; acc 64 -> AGPR side of the
// unified file; total ~224/wave = 2 waves/SIMD, the register-format cap).
// Why 1-wave blocks: the 2 waves/SIMD come from DIFFERENT blocks with
// independent (elided) barriers, so they desynchronize and one wave's LDS
// reads overlap the other's MFMAs — impossible when both waves share one
// block's __syncthreads. __syncthreads on a 64-thread block = bare s_waitcnt.
// B streams through a private 2 x 8KB LDS dbuf, XOR-swizzled 16B chunks.
// MFMA: mfma_scale 16x16x128 f8f6f4 FP8/FP8, unit scales.
// chunk = bid & 7 pins each 1MB fp8 B-chunk to one XCD's L2.
__global__ void __launch_bounds__(64, 2)
gemm_min_kernel(const uint8_t* __restrict__ Ah8, const uint8_t* __restrict__ Bh8,
                const float* __restrict__ sq2, float* __restrict__ ws_min) {
  __shared__ __align__(16) uint8_t lsB[2][BNT * BKP];   // 2 x 8 KB

  const int lane = threadIdx.x;  // 0..63
  const int fr = lane & 15;
  const int kg = lane >> 4;      // 0..3
  const int frs = fr & 7;

  const int bid = blockIdx.x;
  const int chunk = bid & 7;     // == XCD under bid%8 round-robin
  const int rowBase = (bid >> 3) * BM;
  const int colBase0 = chunk * CHUNK_ROWS;

  // Staging: 8 slots of 1KB per phase (slot = 8 cols x 128 B); this wave does
  // all 8. lane -> col-in-slot = lane>>3, 16B chunk = lane&7; swizzle key =
  // col&7 = lane>>3 (matches read-side key frs = fr&7 since col&7 == fr&7).
  const int cis = lane >> 3;
  const int kofs_st = (((lane & 7) ^ cis) << 4);

  // ---- Persistent A fragments: areg[i][p] = row (rowBase + i*16 + fr),
  // k = p*128 + kg*32 .. +32.
  intx8 areg[4][4];
  {
    const uint8_t* abase = Ah8 + (size_t)(rowBase + fr) * KDIM + kg * 32;
    #pragma unroll
    for (int i = 0; i < 4; i++)
      #pragma unroll
      for (int p = 0; p < 4; p++) {
        const uint8_t* ap = abase + (size_t)i * 16 * KDIM + p * BKP;
        intx4 lo = *(const intx4*)ap;
        intx4 hi = *(const intx4*)(ap + 16);
        areg[i][p] = __builtin_shufflevector(lo, hi, 0, 1, 2, 3, 4, 5, 6, 7);
      }
  }

  float runmin[4][4];
  #pragma unroll
  for (int i = 0; i < 4; i++)
    #pragma unroll
    for (int r4 = 0; r4 < 4; r4++) runmin[i][r4] = 3.0e38f;

  // Stage one 64-col x 128-k phase (8 KB): 8 wave-calls.
  #define STAGE_B(buf, cb, kbase_)                                            \
    {                                                                         \
      _Pragma("unroll")                                                       \
      for (int c = 0; c < 8; ++c) {                                           \
        async_ld16(Bh8 + (size_t)((cb) + c * 8 + cis) * KDIM +                \
                       (kbase_) + kofs_st,                                    \
                   (buf) + (c << 10));                                        \
      }                                                                       \
    }

  STAGE_B(lsB[0], colBase0, 0)
  __syncthreads();

  for (int bt = 0; bt < BT_PER_CHUNK; ++bt) {
    const int colBase = colBase0 + bt * BNT;
    floatx4 acc[4][4];
    #pragma unroll
    for (int i = 0; i < 4; i++)
      #pragma unroll
      for (int j = 0; j < 4; j++) acc[i][j] = (floatx4){0.f, 0.f, 0.f, 0.f};

    #pragma unroll
    for (int p = 0; p < 4; ++p) {
      const uint8_t* cur = lsB[p & 1];
      if (p < 3) {
        STAGE_B(lsB[(p + 1) & 1], colBase, (p + 1) * BKP)
      } else if (bt + 1 < BT_PER_CHUNK) {
        STAGE_B(lsB[0], colBase + BNT, 0)
      }
      // Compute phase p: 16 MFMAs.
      #pragma unroll
      for (int j = 0; j < 4; j++) {
        const uint8_t* bp = cur + (j * 16 + fr) * BKP;
        intx4 lo = *(const intx4*)(bp + ((((kg << 1)) ^ frs) << 4));
        intx4 hi = *(const intx4*)(bp + ((((kg << 1) | 1) ^ frs) << 4));
        intx8 bv = __builtin_shufflevector(lo, hi, 0, 1, 2, 3, 4, 5, 6, 7);
        #pragma unroll
        for (int i = 0; i < 4; i++)
          acc[i][j] = __builtin_amdgcn_mfma_scale_f32_16x16x128_f8f6f4(
              areg[i][p], bv, acc[i][j], 0, 0,
              0, UNIT_SCALE, 0, UNIT_SCALE);
      }
      __syncthreads();
    }

    // Epilogue: cand = sq2[col] - 2*inner -> per-row running min.
    #pragma unroll
    for (int j = 0; j < 4; j++) {
      const float s2 = sq2[colBase + j * 16 + fr];
      #pragma unroll
      for (int i = 0; i < 4; i++)
        #pragma unroll
        for (int r4 = 0; r4 < 4; r4++) {
          const float cand = fmaf(-2.f, acc[i][j][r4], s2);
          runmin[i][r4] = fminf(runmin[i][r4], cand);
        }
    }
  }

  // Min over the 16 columns per lane row-group: butterfly on lane bits 0..3.
  #pragma unroll
  for (int i = 0; i < 4; i++)
    #pragma unroll
    for (int r4 = 0; r4 < 4; r4++) {
      float v = runmin[i][r4];
      v = fminf(v, __shfl_xor(v, 1, 64));
      v = fminf(v, __shfl_xor(v, 2, 64));
      v = fminf(v, __shfl_xor(v, 4, 64));
      v = fminf(v, __shfl_xor(v, 8, 64));
      runmin[i][r4] = v;
    }

  if (fr == 0) {
    #pragma unroll
    for (int i = 0; i < 4; i++)
      #pragma unroll
      for (int r4 = 0; r4 < 4; r4++) {
        const int lrow = i * 16 + kg * 4 + r4;
        ws_min[(size_t)chunk * N_ROWS + rowBase + lrow] = runmin[i][r4];
      }
  }
}

// Kernel 3a: per-row min across chunks + sqrt/relu, 64-block partial sums.
__global__ void partial_kernel(const float* __restrict__ ws_min,
                               const float* __restrict__ sq1,
                               float* __restrict__ part) {
  const int r = blockIdx.x * 256 + threadIdx.x;
  float m = ws_min[r];
  #pragma unroll
  for (int c = 1; c < NCHUNK; c++) m = fminf(m, ws_min[(size_t)c * N_ROWS + r]);
  float d2 = sq1[r] + m;
  d2 = d2 > 0.f ? d2 : 0.f;
  float v = sqrtf(d2) - 0.1f;
  float s = v > 0.f ? v : 0.f;
  #pragma unroll
  for (int off = 32; off; off >>= 1) s += __shfl_down(s, off, 64);
  __shared__ float ps[4];
  if ((threadIdx.x & 63) == 0) ps[threadIdx.x >> 6] = s;
  __syncthreads();
  if (threadIdx.x == 0) part[blockIdx.x] = ps[0] + ps[1] + ps[2] + ps[3];
}

// Kernel 3b: combine 64 partials.
__global__ void final_kernel(const float* __restrict__ part, float* __restrict__ out) {
  float s = part[threadIdx.x];
  #pragma unroll
  for (int off = 32; off; off >>= 1) s += __shfl_down(s, off, 64);
  if (threadIdx.x == 0) out[0] = s / (float)N_ROWS;
}

extern "C" void kernel_launch(void* const* d_in, const int* in_sizes, int n_in,
                              void* d_out, int out_size, void* d_ws, size_t ws_size,
                              hipStream_t stream) {
  const float* A = (const float*)d_in[0];
  const float* B = (const float*)d_in[1];
  char* ws = (char*)d_ws;
  const size_t fp8Bytes = (size_t)N_ROWS * KDIM;   // 8 MiB each
  uint8_t* Ah8 = (uint8_t*)ws;
  uint8_t* Bh8 = (uint8_t*)(ws + fp8Bytes);
  float* sq1 = (float*)(ws + 2 * fp8Bytes);
  float* sq2 = sq1 + N_ROWS;
  float* ws_min = sq2 + M_ROWS;
  float* part = ws_min + (size_t)NCHUNK * N_ROWS;

  conv_kernel<<<dim3((N_ROWS + M_ROWS) / 16), dim3(1024), 0, stream>>>(A, B, Ah8, Bh8, sq1, sq2);
  gemm_min_kernel<<<dim3((N_ROWS / BM) * NCHUNK), dim3(64), 0, stream>>>(Ah8, Bh8, sq2, ws_min);
  partial_kernel<<<dim3(64), dim3(256), 0, stream>>>(ws_min, sq1, part);
  final_kernel<<<dim3(1), dim3(64), 0, stream>>>(part, (float*)d_out);
}